// Round 1
// baseline (760.443 us; speedup 1.0000x reference)
//
#include <hip/hip_runtime.h>
#include <cstddef>

static constexpr int CB = 64;    // batch
static constexpr int CN = 512;   // nodes
static constexpr int CD = 256;   // node model dim
static constexpr int CE = 128;   // edge model dim
static constexpr int CIT = 20;   // sinkhorn iterations

// ---------------------------------------------------------------------------
// k0: init v=1, rs=cs=0, and detect the storage layout of the bool mask.
// Detection scans the first 32768 bytes (safe under u8/i32/i64/f32 layouts:
// u8 buffer is exactly 32768 bytes, others are larger) and classifies by which
// byte offsets (mod 4 / mod 8) carry nonzero bytes.
// flag: 0=int32, 1=uint8(bool), 2=float32, 3=int64
// ---------------------------------------------------------------------------
__global__ __launch_bounds__(512) void k0_init(const void* __restrict__ mask,
                                               float* __restrict__ v,
                                               float* __restrict__ rs,
                                               float* __restrict__ cs,
                                               int* __restrict__ flag) {
  const int tid = threadIdx.x;
  if (blockIdx.x < CB) {
    const int idx = blockIdx.x * CN + tid;
    v[idx] = 1.0f;
    rs[idx] = 0.0f;
    cs[idx] = 0.0f;
  } else {
    __shared__ int cnt[5];
    if (tid < 5) cnt[tid] = 0;
    __syncthreads();
    const unsigned char* p = (const unsigned char*)mask;
    int l0 = 0, l1 = 0, l2 = 0, l3 = 0, l4 = 0;
    const int base = tid * 64;
    for (int k = 0; k < 64; ++k) {
      const int off = base + k;
      if (p[off]) {
        const int m4 = off & 3;
        if (m4 == 1) l1++;
        else if (m4 == 2) l2++;
        else if (m4 == 3) l3++;
        else if ((off & 7) == 4) l4++;
        else l0++;
      }
    }
    if (l0) atomicAdd(&cnt[0], 1);
    if (l1) atomicAdd(&cnt[1], 1);
    if (l2) atomicAdd(&cnt[2], 1);
    if (l3) atomicAdd(&cnt[3], 1);
    if (l4) atomicAdd(&cnt[4], 1);
    __syncthreads();
    if (tid == 0) {
      int f;
      if (cnt[1]) f = 1;                 // nonzero at odd offsets -> 1-byte bool
      else if (cnt[2] || cnt[3]) f = 2;  // nonzero only at +2/+3 -> f32 (0x3F80..)
      else if (cnt[4]) f = 0;            // nonzero at 4 mod 8 -> int32
      else if (cnt[0]) f = 3;            // nonzero only at 0 mod 8 -> int64
      else f = 1;                        // all-zero: every layout agrees; u8 safest
      *flag = f;
    }
  }
}

// ---------------------------------------------------------------------------
// prep_gemm: out[row, e] over rows = b*N+i (M=32768), K=D=256, Ncols=E=128.
// MODE 0 (A path): x = out_emb + pos,       out = (x @ W) * w_aff
// MODE 1 (B path): x = mask ? pad : in_emb, out =  x @ W
// Tile: 64 rows x 128 cols, K-chunks of 64. 256 threads, 4x8 acc/thread.
// ---------------------------------------------------------------------------
template <int MODE>
__global__ __launch_bounds__(256) void prep_gemm(
    const float* __restrict__ X, const float* __restrict__ extra,
    const void* __restrict__ maskp, const int* __restrict__ flagp,
    const float* __restrict__ W, const float* __restrict__ w_aff,
    float* __restrict__ out) {
  __shared__ float Xs[64][65];                 // +1 pad, scalar access
  __shared__ alignas(16) float Ws[64][CE];     // float4 access
  const int tid = threadIdx.x;
  const int row0 = blockIdx.x * 64;
  const int tx = tid & 15, ty = tid >> 4;
  const int flag = (MODE == 1) ? *flagp : 0;
  float acc[4][8];
#pragma unroll
  for (int a = 0; a < 4; ++a)
#pragma unroll
    for (int c = 0; c < 8; ++c) acc[a][c] = 0.0f;

  for (int kc = 0; kc < CD; kc += 64) {
    // stage X chunk (64 rows x 64 k), fused elementwise prolog
    {
      const int lk = tid & 15;   // float4 index (16*4 = 64 k)
      const int rp = tid >> 4;   // 16 rows/pass
#pragma unroll
      for (int pass = 0; pass < 4; ++pass) {
        const int r = pass * 16 + rp;
        const int row = row0 + r;
        const int i = row & (CN - 1);
        const int d = kc + lk * 4;
        float4 x4;
        if (MODE == 0) {
          x4 = *(const float4*)&X[(size_t)row * CD + d];
          const float4 p4 = *(const float4*)&extra[(size_t)i * CD + d];
          x4.x += p4.x; x4.y += p4.y; x4.z += p4.z; x4.w += p4.w;
        } else {
          bool m;
          if (flag == 1)      m = ((const unsigned char*)maskp)[row] != 0;
          else if (flag == 2) m = ((const float*)maskp)[row] != 0.0f;
          else if (flag == 3) m = ((const long long*)maskp)[row] != 0;
          else                m = ((const int*)maskp)[row] != 0;
          if (m) x4 = *(const float4*)&extra[d];
          else   x4 = *(const float4*)&X[(size_t)row * CD + d];
        }
        Xs[r][lk * 4 + 0] = x4.x; Xs[r][lk * 4 + 1] = x4.y;
        Xs[r][lk * 4 + 2] = x4.z; Xs[r][lk * 4 + 3] = x4.w;
      }
    }
    // stage W chunk (64 k x 128 cols)
    {
      const int cv = tid & 31;   // 32 float4 = 128 cols
      const int kr = tid >> 5;   // 8 k-rows/pass
#pragma unroll
      for (int pass = 0; pass < 8; ++pass) {
        const int kk = pass * 8 + kr;
        *(float4*)&Ws[kk][cv * 4] = *(const float4*)&W[(size_t)(kc + kk) * CE + cv * 4];
      }
    }
    __syncthreads();
#pragma unroll 4
    for (int kk = 0; kk < 64; ++kk) {
      float xa[4];
#pragma unroll
      for (int a = 0; a < 4; ++a) xa[a] = Xs[ty * 4 + a][kk];
      const float4 wb0 = *(const float4*)&Ws[kk][tx * 8];
      const float4 wb1 = *(const float4*)&Ws[kk][tx * 8 + 4];
      const float wb[8] = {wb0.x, wb0.y, wb0.z, wb0.w, wb1.x, wb1.y, wb1.z, wb1.w};
#pragma unroll
      for (int a = 0; a < 4; ++a)
#pragma unroll
        for (int c = 0; c < 8; ++c) acc[a][c] += xa[a] * wb[c];
    }
    __syncthreads();
  }
  float wa[8];
  if (MODE == 0) {
#pragma unroll
    for (int c = 0; c < 8; ++c) wa[c] = w_aff[tx * 8 + c];
  }
#pragma unroll
  for (int a = 0; a < 4; ++a) {
    const int row = row0 + ty * 4 + a;
    float o[8];
#pragma unroll
    for (int c = 0; c < 8; ++c) o[c] = (MODE == 0) ? acc[a][c] * wa[c] : acc[a][c];
    *(float4*)&out[(size_t)row * CE + tx * 8]     = make_float4(o[0], o[1], o[2], o[3]);
    *(float4*)&out[(size_t)row * CE + tx * 8 + 4] = make_float4(o[4], o[5], o[6], o[7]);
  }
}

// ---------------------------------------------------------------------------
// aff_exp: per batch b, E[i,j] = exp(A[i,:]·Bm[j,:] + b_aff) written to d_out,
// plus atomic row sums rs[b,i] (softmax axis=2 denom) and column sums cs[b,j]
// (softmax axis=1 denom). Tile 64x64, K=128 fully staged. 256 thr, 4x4/thread,
// thread's local cols j = tx + 16c (stride-16 to keep LDS reads 2-way max).
// ---------------------------------------------------------------------------
__global__ __launch_bounds__(256) void aff_exp(
    const float* __restrict__ A, const float* __restrict__ Bm,
    const float* __restrict__ baff, float* __restrict__ E,
    float* __restrict__ rs, float* __restrict__ cs) {
  __shared__ alignas(16) float As[64][132];
  __shared__ alignas(16) float Bs[64][132];
  const int tid = threadIdx.x;
  const int b = blockIdx.x >> 6;
  const int tile = blockIdx.x & 63;
  const int i0 = (tile >> 3) * 64;
  const int j0 = (tile & 7) * 64;
  {
    const int cv = tid & 31;   // k float4 idx
    const int rp = tid >> 5;   // 8 rows/pass
#pragma unroll
    for (int pass = 0; pass < 8; ++pass) {
      const int r = pass * 8 + rp;
      *(float4*)&As[r][cv * 4] = *(const float4*)&A[((size_t)b * CN + i0 + r) * CE + cv * 4];
      *(float4*)&Bs[r][cv * 4] = *(const float4*)&Bm[((size_t)b * CN + j0 + r) * CE + cv * 4];
    }
  }
  __syncthreads();
  const int tx = tid & 15, ty = tid >> 4;
  float acc[4][4];
#pragma unroll
  for (int a = 0; a < 4; ++a)
#pragma unroll
    for (int c = 0; c < 4; ++c) acc[a][c] = 0.0f;
#pragma unroll 4
  for (int k4 = 0; k4 < CE / 4; ++k4) {
    float4 a4[4], b4[4];
#pragma unroll
    for (int a = 0; a < 4; ++a) a4[a] = *(const float4*)&As[ty * 4 + a][k4 * 4];
#pragma unroll
    for (int c = 0; c < 4; ++c) b4[c] = *(const float4*)&Bs[tx + 16 * c][k4 * 4];
#pragma unroll
    for (int a = 0; a < 4; ++a)
#pragma unroll
      for (int c = 0; c < 4; ++c)
        acc[a][c] += a4[a].x * b4[c].x + a4[a].y * b4[c].y +
                     a4[a].z * b4[c].z + a4[a].w * b4[c].w;
  }
  const float bb = *baff;
  float ev[4][4];
  float rsum[4] = {0, 0, 0, 0}, csum[4] = {0, 0, 0, 0};
#pragma unroll
  for (int a = 0; a < 4; ++a)
#pragma unroll
    for (int c = 0; c < 4; ++c) {
      const float e = __expf(acc[a][c] + bb);
      ev[a][c] = e;
      rsum[a] += e;
      csum[c] += e;
    }
#pragma unroll
  for (int a = 0; a < 4; ++a) {
    const int i = i0 + ty * 4 + a;
    float* dst = &E[((size_t)b * CN + i) * CN + j0];
#pragma unroll
    for (int c = 0; c < 4; ++c) dst[tx + 16 * c] = ev[a][c];
  }
  // block-level reduce then one atomic per row / per col
  __syncthreads();
  float* red = &As[0][0];   // reuse: [64][17]
#pragma unroll
  for (int a = 0; a < 4; ++a) red[(ty * 4 + a) * 17 + tx] = rsum[a];
  __syncthreads();
  if (tid < 64) {
    float s = 0;
#pragma unroll
    for (int t = 0; t < 16; ++t) s += red[tid * 17 + t];
    atomicAdd(&rs[b * CN + i0 + tid], s);
  }
  __syncthreads();
#pragma unroll
  for (int c = 0; c < 4; ++c) red[(tx + 16 * c) * 17 + ty] = csum[c];
  __syncthreads();
  if (tid < 64) {
    float s = 0;
#pragma unroll
    for (int t = 0; t < 16; ++t) s += red[tid * 17 + t];
    atomicAdd(&cs[b * CN + j0 + tid], s);
  }
}

// ---------------------------------------------------------------------------
// Sinkhorn u-phase: u[b,i] = 1 / sum_j K[i,j] v[j]
//   = 1 / ( sum_j E_ij*(0.5 v_j/cs_j)  +  (0.5/rs_i) * sum_j E_ij*v_j )
// block 256 = 4 waves x 4 rows; row dot via float4 + wave shuffle reduce.
// ---------------------------------------------------------------------------
__global__ __launch_bounds__(256) void u_update(
    const float* __restrict__ E, const float* __restrict__ v,
    const float* __restrict__ cs, const float* __restrict__ rs,
    float* __restrict__ u) {
  __shared__ alignas(16) float w1[CN];
  __shared__ alignas(16) float w2[CN];
  const int tid = threadIdx.x;
  const int b = blockIdx.x >> 5;
  const int i0 = (blockIdx.x & 31) * 16;
#pragma unroll
  for (int t = 0; t < 2; ++t) {
    const int j = t * 256 + tid;
    const float vv = v[b * CN + j];
    w2[j] = vv;
    w1[j] = 0.5f * vv / cs[b * CN + j];
  }
  __syncthreads();
  const int wid = tid >> 6, lane = tid & 63;
#pragma unroll
  for (int rr = 0; rr < 4; ++rr) {
    const int i = i0 + wid * 4 + rr;
    const float* Erow = &E[((size_t)b * CN + i) * CN];
    float a1 = 0, a2 = 0;
#pragma unroll
    for (int m = 0; m < 2; ++m) {
      const int j = m * 256 + lane * 4;
      const float4 e4 = *(const float4*)&Erow[j];
      const float4 x1 = *(const float4*)&w1[j];
      const float4 x2 = *(const float4*)&w2[j];
      a1 += e4.x * x1.x + e4.y * x1.y + e4.z * x1.z + e4.w * x1.w;
      a2 += e4.x * x2.x + e4.y * x2.y + e4.z * x2.z + e4.w * x2.w;
    }
#pragma unroll
    for (int o = 32; o > 0; o >>= 1) {
      a1 += __shfl_down(a1, o);
      a2 += __shfl_down(a2, o);
    }
    if (lane == 0) {
      u[b * CN + i] = 1.0f / (a1 + 0.5f * a2 / rs[b * CN + i]);
    }
  }
}

// ---------------------------------------------------------------------------
// Sinkhorn v-phase: v[b,j] = 1 / sum_i K[i,j] u[i]
//   = 1 / ( (0.5/cs_j)*sum_i E_ij u_i  +  0.5*sum_i E_ij*(u_i/rs_i) )
// block 256 = 4 waves, each wave owns 64 cols over a 128-row range; columns
// are lane-contiguous so E reads stay coalesced without a transpose.
// ---------------------------------------------------------------------------
__global__ __launch_bounds__(256) void v_update(
    const float* __restrict__ E, const float* __restrict__ u,
    const float* __restrict__ rs, const float* __restrict__ cs,
    float* __restrict__ v) {
  __shared__ float u1[CN];
  __shared__ float u2[CN];
  __shared__ float red[2][4][64];
  const int tid = threadIdx.x;
  const int b = blockIdx.x >> 3;
  const int j0 = (blockIdx.x & 7) * 64;
#pragma unroll
  for (int t = 0; t < 2; ++t) {
    const int i = t * 256 + tid;
    const float uu = u[b * CN + i];
    u1[i] = uu;
    u2[i] = uu / rs[b * CN + i];
  }
  __syncthreads();
  const int wid = tid >> 6, lane = tid & 63;
  float t1 = 0, t2 = 0;
  const float* Eb = &E[(size_t)b * CN * CN];
  for (int ii = 0; ii < 128; ++ii) {
    const int i = wid * 128 + ii;
    const float e = Eb[(size_t)i * CN + j0 + lane];
    t1 += e * u1[i];
    t2 += e * u2[i];
  }
  red[0][wid][lane] = t1;
  red[1][wid][lane] = t2;
  __syncthreads();
  if (tid < 64) {
    const int j = j0 + tid;
    const float s1 = red[0][0][tid] + red[0][1][tid] + red[0][2][tid] + red[0][3][tid];
    const float s2 = red[1][0][tid] + red[1][1][tid] + red[1][2][tid] + red[1][3][tid];
    v[b * CN + j] = 1.0f / (0.5f * s1 / cs[b * CN + j] + 0.5f * s2);
  }
}

// ---------------------------------------------------------------------------
// finalize (in place on d_out): P_ij = E_ij * u_i * v_j * (0.5/cs_j + 0.5/rs_i)
// ---------------------------------------------------------------------------
__global__ __launch_bounds__(256) void finalize(
    float* __restrict__ P, const float* __restrict__ u,
    const float* __restrict__ v, const float* __restrict__ rs,
    const float* __restrict__ cs) {
  const size_t idx = ((size_t)blockIdx.x * blockDim.x + threadIdx.x) * 4;
  const size_t j = idx & (CN - 1);
  const size_t row = idx >> 9;       // b*N + i
  const size_t b = row >> 9;
  const float4 e4 = *(const float4*)&P[idx];
  const float ui = u[row];
  const float ri = 0.5f / rs[row];
  const float4 v4 = *(const float4*)&v[b * CN + j];
  const float4 c4 = *(const float4*)&cs[b * CN + j];
  float4 o;
  o.x = e4.x * ui * v4.x * (0.5f / c4.x + ri);
  o.y = e4.y * ui * v4.y * (0.5f / c4.y + ri);
  o.z = e4.z * ui * v4.z * (0.5f / c4.z + ri);
  o.w = e4.w * ui * v4.w * (0.5f / c4.w + ri);
  *(float4*)&P[idx] = o;
}

// ---------------------------------------------------------------------------
extern "C" void kernel_launch(void* const* d_in, const int* in_sizes, int n_in,
                              void* d_out, int out_size, void* d_ws, size_t ws_size,
                              hipStream_t stream) {
  const float* in_emb  = (const float*)d_in[0];   // [B,N,D]
  const void*  mask    = d_in[1];                 // [B,N] bool-ish
  const float* out_emb = (const float*)d_in[2];   // [B,N,D]
  const float* pad     = (const float*)d_in[3];   // [1,1,D]
  const float* pos     = (const float*)d_in[4];   // [1,N,D]
  const float* W_a     = (const float*)d_in[5];   // [D,E]
  const float* W_b     = (const float*)d_in[6];   // [D,E]
  const float* w_aff   = (const float*)d_in[7];   // [E]
  const float* b_aff   = (const float*)d_in[8];   // scalar
  float* P = (float*)d_out;                       // [B,N,N]; also holds E=exp(aff)
  float* ws = (float*)d_ws;

  float* A  = ws;                          // [B*N, E] = 4,194,304 floats
  float* Bm = ws + (size_t)CB * CN * CE;   // [B*N, E]
  float* rs = Bm + (size_t)CB * CN * CE;   // [B*N]
  float* cs = rs + CB * CN;                // [B*N]
  float* u  = cs + CB * CN;                // [B*N]
  float* v  = u + CB * CN;                 // [B*N]
  int* flag = (int*)(v + CB * CN);

  k0_init<<<dim3(CB + 1), dim3(512), 0, stream>>>(mask, v, rs, cs, flag);
  prep_gemm<0><<<dim3(CB * CN / 64), dim3(256), 0, stream>>>(
      out_emb, pos, nullptr, flag, W_a, w_aff, A);
  prep_gemm<1><<<dim3(CB * CN / 64), dim3(256), 0, stream>>>(
      in_emb, pad, mask, flag, W_b, nullptr, Bm);
  aff_exp<<<dim3(CB * 64), dim3(256), 0, stream>>>(A, Bm, b_aff, P, rs, cs);
  for (int it = 0; it < CIT; ++it) {
    u_update<<<dim3(CB * 32), dim3(256), 0, stream>>>(P, v, cs, rs, u);
    v_update<<<dim3(CB * 8), dim3(256), 0, stream>>>(P, u, rs, cs, v);
  }
  finalize<<<dim3(CB * CN * CN / 4 / 256), dim3(256), 0, stream>>>(P, u, v, rs, cs);
}